// Round 1
// baseline (975.846 us; speedup 1.0000x reference)
//
#include <hip/hip_runtime.h>
#include <hip/hip_bf16.h>

typedef unsigned short u16;
typedef unsigned int u32;
typedef __attribute__((ext_vector_type(8))) short s16x8;   // 8 bf16 (4 VGPRs)
typedef __attribute__((ext_vector_type(4))) float f32x4;

__device__ __forceinline__ u16 bf16bits(float v) {
    union { __hip_bfloat16 b; u16 u; } c;
    c.b = __float2bfloat16(v);
    return c.u;
}

// Reference-exact discretize (validated rounds 2-4).
__device__ __forceinline__ float disc1(float v, float mn, float rg, float s) {
    const float u = __fmul_rn(__fsub_rn(v, mn), s);
    const float rn = rintf(u);
    int idx;
    if (fabsf(u - rn) > 1e-3f) {
        idx = (int)ceilf(u) - 1;
    } else {
        int kc = (int)rn;
        kc = kc < 1 ? 1 : (kc > 24 ? 24 : kc);
        const float cf = __fdiv_rn((float)kc, 25.0f);
        const float b = __fadd_rn(mn, __fmul_rn(rg, cf));
        idx = (int)rn - 1 + ((b < v) ? 1 : 0);
    }
    idx = idx < 0 ? 0 : (idx > 24 ? 24 : idx);
    return (float)idx;
}

// ---------------- per-column min/max: 1024 blocks x 128 rows ----------------
__global__ void kminmax(const float* __restrict__ x, float* __restrict__ pmin,
                        float* __restrict__ pmax) {
    __shared__ float4 smn[512], smx[512];
    const int t = threadIdx.x;
    const int c4 = t & 127;
    const int ro = t >> 7;
    const size_t r0 = (size_t)blockIdx.x * 128;
    float4 mn = {1e30f, 1e30f, 1e30f, 1e30f};
    float4 mx = {-1e30f, -1e30f, -1e30f, -1e30f};
#pragma unroll 8
    for (int i = 0; i < 32; ++i) {
        const int row = ro + i * 4;
        const float4 v = ((const float4*)(x + (r0 + row) * 512))[c4];
        mn.x = fminf(mn.x, v.x); mn.y = fminf(mn.y, v.y);
        mn.z = fminf(mn.z, v.z); mn.w = fminf(mn.w, v.w);
        mx.x = fmaxf(mx.x, v.x); mx.y = fmaxf(mx.y, v.y);
        mx.z = fmaxf(mx.z, v.z); mx.w = fmaxf(mx.w, v.w);
    }
    smn[t] = mn; smx[t] = mx;
    __syncthreads();
    if (t < 128) {
#pragma unroll
        for (int p = 1; p < 4; ++p) {
            const float4 a = smn[t + p * 128], b = smx[t + p * 128];
            mn.x = fminf(mn.x, a.x); mn.y = fminf(mn.y, a.y);
            mn.z = fminf(mn.z, a.z); mn.w = fminf(mn.w, a.w);
            mx.x = fmaxf(mx.x, b.x); mx.y = fmaxf(mx.y, b.y);
            mx.z = fmaxf(mx.z, b.z); mx.w = fmaxf(mx.w, b.w);
        }
        ((float4*)(pmin + blockIdx.x * 512))[c4] = mn;
        ((float4*)(pmax + blockIdx.x * 512))[c4] = mx;
    }
}

__global__ void kred(const float* __restrict__ pmin, const float* __restrict__ pmax,
                     float* __restrict__ p2min, float* __restrict__ p2max, int per) {
    const int c = threadIdx.x;
    const int j = blockIdx.x;
    float mn = 1e30f, mx = -1e30f;
    for (int i = 0; i < per; ++i) {
        mn = fminf(mn, pmin[(size_t)(j * per + i) * 512 + c]);
        mx = fmaxf(mx, pmax[(size_t)(j * per + i) * 512 + c]);
    }
    p2min[j * 512 + c] = mn;
    p2max[j * 512 + c] = mx;
}

__global__ void kbounds(const float* __restrict__ p2min, const float* __restrict__ p2max,
                        float* __restrict__ cmin, float* __restrict__ crange,
                        float* __restrict__ sinv, int np, float* __restrict__ dloss) {
    const int c = threadIdx.x;
    float mn = 1e30f, mx = -1e30f;
    for (int p = 0; p < np; ++p) {
        mn = fminf(mn, p2min[p * 512 + c]);
        mx = fmaxf(mx, p2max[p * 512 + c]);
    }
    cmin[c] = mn;
    const float rg = __fsub_rn(mx, mn);
    crange[c] = rg;
    sinv[c] = __fdiv_rn(25.0f, rg);
    if (c == 0) dloss[0] = 0.0f;          // d2_loss
}

// ---------------- weight casts W[K,N] fp32 -> Wt[N,K] bf16 ----------------
__global__ void ktc_all(const float* __restrict__ W_in, const float* __restrict__ W_h,
                        const float* __restrict__ W_out,
                        __hip_bfloat16* __restrict__ WinT, __hip_bfloat16* __restrict__ WhT,
                        __hip_bfloat16* __restrict__ WoutT) {
    const int i = blockIdx.x * 256 + threadIdx.x;
    if (i < 512 * 512) {
        WinT[i] = __float2bfloat16(W_in[(size_t)(i & 511) * 512 + (i >> 9)]);
    } else if (i < 2 * 512 * 512) {
        const int j = i - 512 * 512;
        WhT[j] = __float2bfloat16(W_h[(size_t)(j & 511) * 512 + (j >> 9)]);
    } else if (i < 2 * 512 * 512 + 128 * 512) {
        const int j = i - 2 * 512 * 512;
        WoutT[j] = __float2bfloat16(W_out[(size_t)(j & 511) * 128 + (j >> 9)]);
    }
}

// ---------------- Fused discretize + 7-layer MLP, 128 rows/block ----------------
// Block = 128 batch rows (two 64-row LDS act buffers, IN-PLACE layer update:
// phase A reads everything into acc, barrier, phase B overwrites, barrier).
// Wave w computes neurons w*64..w*64+63 for ALL 128 batch rows.
// NEW this round: activation (bF) fragments are double-buffered across ks,
// exactly like the weight (aF/aN) fragments already were. Each ks issues the
// NEXT iteration's 8 ds_read_b128 + 4 global loads BEFORE executing the
// current 32 MFMAs, so the lgkmcnt wait hides behind ~1.2K cyc of MFMA issue
// (per-wave ILP — works at 2 waves/SIMD lockstep). Accumulation order per
// output is unchanged -> bit-identical numerics.
// Act layout per 64-row buffer: [row][k] bf16, 16B granule g at g^(row&7).
__global__ __launch_bounds__(512, 2) void megamlp(
    const float* __restrict__ x,
    const float* __restrict__ cmin, const float* __restrict__ crange,
    const float* __restrict__ sinv,
    const u16* __restrict__ WinT, const u16* __restrict__ WhT,
    const u16* __restrict__ WoutT,
    const float* __restrict__ b_in, const float* __restrict__ b_h,
    const float* __restrict__ b_out,
    float* __restrict__ out) {
    __shared__ __attribute__((aligned(16))) u16 actA[64 * 512];   // 64 KB
    __shared__ __attribute__((aligned(16))) u16 actB[64 * 512];   // 64 KB

    const int t = threadIdx.x;
    const int lane = t & 63;
    const int w = t >> 6;          // wave 0..7
    const int lr = lane & 15;
    const int kq = lane >> 4;      // 0..3
    const int xr = lr & 7;
    const size_t row0 = (size_t)blockIdx.x * 128;

    // ---- discretize 128 rows of x into actA (rows 0-63) / actB (64-127) ----
    {
        const int c4 = t & 127;
        const int ro = t >> 7;             // 0..3
        const float4 mn4 = ((const float4*)cmin)[c4];
        const float4 rg4 = ((const float4*)crange)[c4];
        const float4 s4  = ((const float4*)sinv)[c4];
        const int g16 = c4 >> 1;
        const int hb  = (c4 & 1) << 3;
#pragma unroll 8
        for (int i = 0; i < 32; ++i) {
            const int row = ro + i * 4;          // 0..127
            const float4 v = ((const float4*)(x + (row0 + row) * 512))[c4];
            const u32 lo = (u32)bf16bits(disc1(v.x, mn4.x, rg4.x, s4.x))
                         | ((u32)bf16bits(disc1(v.y, mn4.y, rg4.y, s4.y)) << 16);
            const u32 hi = (u32)bf16bits(disc1(v.z, mn4.z, rg4.z, s4.z))
                         | ((u32)bf16bits(disc1(v.w, mn4.w, rg4.w, s4.w)) << 16);
            const int rl = row & 63;
            const int gg = g16 ^ (rl & 7);
            char* base = (row < 64) ? (char*)actA : (char*)actB;
            *(uint2*)(base + (rl << 10) + (gg << 4) + hb) = make_uint2(lo, hi);
        }
    }
    __syncthreads();

    // ---- 6 hidden-shaped layers (512 -> 512), in-place ----
    for (int layer = 0; layer < 6; ++layer) {
        const u16* W = (layer == 0) ? WinT : WhT;
        const float* bias = (layer == 0) ? b_in : b_h;

        f32x4 acc[2][4][4] = {};
        const u16* wp0 = W + ((w * 64 + lr) << 9) + (kq << 3);

        // hoist bias into regs during phase A (keeps it out of the
        // post-barrier convoy)
        f32x4 bv4[4];
#pragma unroll
        for (int mt = 0; mt < 4; ++mt)
            bv4[mt] = ((const f32x4*)bias)[w * 16 + mt * 4 + kq];

        s16x8 aF[4], aN[4];
        s16x8 bF[2][4], bN[2][4];
#pragma unroll
        for (int mt = 0; mt < 4; ++mt)
            aF[mt] = *(const s16x8*)(wp0 + (mt << 13));
        {
            const int gg = kq ^ xr;   // ks = 0
#pragma unroll
            for (int h = 0; h < 2; ++h) {
                const char* ah = h ? (const char*)actB : (const char*)actA;
#pragma unroll
                for (int nt = 0; nt < 4; ++nt)
                    bF[h][nt] = *(const s16x8*)(ah + ((nt * 16 + lr) << 10) + (gg << 4));
            }
        }

#pragma unroll
        for (int ks = 0; ks < 16; ++ks) {
            // prefetch NEXT iteration's weights + activations first
            if (ks < 15) {
                const u16* wn = wp0 + (ks + 1) * 32;
#pragma unroll
                for (int mt = 0; mt < 4; ++mt)
                    aN[mt] = *(const s16x8*)(wn + (mt << 13));
                const int gn = (((ks + 1) << 2) | kq) ^ xr;
#pragma unroll
                for (int h = 0; h < 2; ++h) {
                    const char* ah = h ? (const char*)actB : (const char*)actA;
#pragma unroll
                    for (int nt = 0; nt < 4; ++nt)
                        bN[h][nt] = *(const s16x8*)(ah + ((nt * 16 + lr) << 10) + (gn << 4));
                }
            }
            // current MFMAs consume already-resident registers
#pragma unroll
            for (int h = 0; h < 2; ++h)
#pragma unroll
                for (int mt = 0; mt < 4; ++mt)
#pragma unroll
                    for (int nt = 0; nt < 4; ++nt)
                        acc[h][mt][nt] = __builtin_amdgcn_mfma_f32_16x16x32_bf16(
                            aF[mt], bF[h][nt], acc[h][mt][nt], 0, 0, 0);
#pragma unroll
            for (int mt = 0; mt < 4; ++mt) aF[mt] = aN[mt];
#pragma unroll
            for (int h = 0; h < 2; ++h)
#pragma unroll
                for (int nt = 0; nt < 4; ++nt) bF[h][nt] = bN[h][nt];
        }
        __syncthreads();   // all reads done -> safe to overwrite in place

        // phase B: bias + relu -> bf16 -> act[batch][neuron-as-k], swizzled
#pragma unroll
        for (int mt = 0; mt < 4; ++mt) {
            const int g16 = w * 8 + mt * 2 + (kq >> 1);
#pragma unroll
            for (int h = 0; h < 2; ++h) {
                char* ah = h ? (char*)actB : (char*)actA;
#pragma unroll
                for (int nt = 0; nt < 4; ++nt) {
                    const int batch = nt * 16 + lr;
                    const float v0 = fmaxf(acc[h][mt][nt][0] + bv4[mt][0], 0.0f);
                    const float v1 = fmaxf(acc[h][mt][nt][1] + bv4[mt][1], 0.0f);
                    const float v2 = fmaxf(acc[h][mt][nt][2] + bv4[mt][2], 0.0f);
                    const float v3 = fmaxf(acc[h][mt][nt][3] + bv4[mt][3], 0.0f);
                    const u32 lo = (u32)bf16bits(v0) | ((u32)bf16bits(v1) << 16);
                    const u32 hi = (u32)bf16bits(v2) | ((u32)bf16bits(v3) << 16);
                    const int gg = g16 ^ (batch & 7);
                    *(uint2*)(ah + (batch << 10) + (gg << 4) + ((kq & 1) << 3)) =
                        make_uint2(lo, hi);
                }
            }
        }
        __syncthreads();
    }

    // ---- output layer: 128 neurons; wave w -> neurons w*16..w*16+15 ----
    {
        f32x4 acc[2][4] = {};
        const u16* wp = WoutT + ((w * 16 + lr) << 9) + (kq << 3);
        const f32x4 bvo = ((const f32x4*)b_out)[w * 4 + kq];
        s16x8 aF = *(const s16x8*)(wp), aN;
        s16x8 bF[2][4], bN[2][4];
        {
            const int gg = kq ^ xr;   // ks = 0
#pragma unroll
            for (int h = 0; h < 2; ++h) {
                const char* ah = h ? (const char*)actB : (const char*)actA;
#pragma unroll
                for (int nt = 0; nt < 4; ++nt)
                    bF[h][nt] = *(const s16x8*)(ah + ((nt * 16 + lr) << 10) + (gg << 4));
            }
        }
#pragma unroll
        for (int ks = 0; ks < 16; ++ks) {
            if (ks < 15) {
                aN = *(const s16x8*)(wp + (ks + 1) * 32);
                const int gn = (((ks + 1) << 2) | kq) ^ xr;
#pragma unroll
                for (int h = 0; h < 2; ++h) {
                    const char* ah = h ? (const char*)actB : (const char*)actA;
#pragma unroll
                    for (int nt = 0; nt < 4; ++nt)
                        bN[h][nt] = *(const s16x8*)(ah + ((nt * 16 + lr) << 10) + (gn << 4));
                }
            }
#pragma unroll
            for (int h = 0; h < 2; ++h)
#pragma unroll
                for (int nt = 0; nt < 4; ++nt)
                    acc[h][nt] = __builtin_amdgcn_mfma_f32_16x16x32_bf16(
                        aF, bF[h][nt], acc[h][nt], 0, 0, 0);
            aF = aN;
#pragma unroll
            for (int h = 0; h < 2; ++h)
#pragma unroll
                for (int nt = 0; nt < 4; ++nt) bF[h][nt] = bN[h][nt];
        }
        __syncthreads();   // reads done; stage fp32 [64][128] per half in place

        const int g16o = w * 4 + kq;
#pragma unroll
        for (int h = 0; h < 2; ++h) {
            char* sh = h ? (char*)actB : (char*)actA;
#pragma unroll
            for (int nt = 0; nt < 4; ++nt) {
                const int batch = nt * 16 + lr;
                const int gg = g16o ^ (batch & 7);
                float* p = (float*)(sh + (batch << 9) + (gg << 4));
#pragma unroll
                for (int r = 0; r < 4; ++r)
                    p[r] = fmaxf(acc[h][nt][r] + bvo[r], 0.0f);
            }
        }
    }
    __syncthreads();

    // ---- coalesced dump of staged 2x[64][128] fp32 ----
    {
        const int n4 = t & 31;
        const int bo = t >> 5;          // 0..15
#pragma unroll
        for (int h = 0; h < 2; ++h) {
            const char* sh = h ? (const char*)actB : (const char*)actA;
#pragma unroll
            for (int pp = 0; pp < 4; ++pp) {
                const int batch = pp * 16 + bo;
                const int gg = n4 ^ (batch & 7);
                const float4 v = *(const float4*)(sh + (batch << 9) + (gg << 4));
                ((float4*)(out + (row0 + h * 64 + batch) * 128))[n4] = v;
            }
        }
    }
}

extern "C" void kernel_launch(void* const* d_in, const int* in_sizes, int n_in,
                              void* d_out, int out_size, void* d_ws, size_t ws_size,
                              hipStream_t stream) {
    const float* x     = (const float*)d_in[0];
    const float* W_in  = (const float*)d_in[1];
    const float* b_in  = (const float*)d_in[2];
    const float* W_h   = (const float*)d_in[3];
    const float* b_h   = (const float*)d_in[4];
    const float* W_out = (const float*)d_in[5];
    const float* b_out = (const float*)d_in[6];
    float* out = (float*)d_out;

    const int B = in_sizes[0] / 512;       // 131072
    const int NP1 = B / 128;               // 1024 minmax partial blocks

    // workspace (~5.5 MB)
    __hip_bfloat16* WinT  = (__hip_bfloat16*)d_ws;           // 512*512
    __hip_bfloat16* WhT   = WinT + 512 * 512;                // 512*512
    __hip_bfloat16* WoutT = WhT + 512 * 512;                 // 128*512
    float* pmin   = (float*)(WoutT + 128 * 512);             // NP1*512
    float* pmax   = pmin + (size_t)NP1 * 512;                // NP1*512
    float* p2min  = pmax + (size_t)NP1 * 512;                // 64*512
    float* p2max  = p2min + 64 * 512;                        // 64*512
    float* cmin   = p2max + 64 * 512;                        // 512
    float* crange = cmin + 512;                              // 512
    float* sinv   = crange + 512;                            // 512

    kminmax<<<NP1, 512, 0, stream>>>(x, pmin, pmax);
    kred<<<64, 512, 0, stream>>>(pmin, pmax, p2min, p2max, NP1 / 64);
    kbounds<<<1, 512, 0, stream>>>(p2min, p2max, cmin, crange, sinv, 64,
                                   out + (size_t)B * 128);
    ktc_all<<<(2 * 512 * 512 + 128 * 512 + 255) / 256, 256, 0, stream>>>(
        W_in, W_h, W_out, WinT, WhT, WoutT);

    megamlp<<<B / 128, 512, 0, stream>>>(x, cmin, crange, sinv,
        (const u16*)WinT, (const u16*)WhT, (const u16*)WoutT,
        b_in, b_h, b_out, out);
}